// Round 8
// baseline (295.800 us; speedup 1.0000x reference)
//
#include <hip/hip_runtime.h>
#include <hip/hip_fp16.h>

// Problem geometry: inputs (B=2, D=64, H=64, W=64, C=32) fp32, C innermost.
// Pass1: Sobel (VALID) -> mag = sqrt(gx^2+gy^2+gz^2) at 62^3 per (b,c)
// Pass2: Sobel on mag -> out = sqrt(gx^2+gy^2) + gz^2 at 60^3
// Result: mean(|out_pred - out_hr|) over 2*32*60^3 = 13,824,000 elems.
//
// R12: wave-count x2 at IDENTICAL per-thread efficiency. R11 confounded
// wave-count with a 1.5x worse inner loop (9 vs 6 loads/output-row) and
// regressed; R5 confounded it with working-set. This round: R7-P1 and R4-P2
// bodies VERBATIM, z-chunk halved only (P1: 8->4, grid (62,16,2); P2: 10->5,
// grid (120,12)). Same loads/output (+17-20% z-halo), 2x blocks, 2x waves.
// Hypothesis: latency-exposure bound -> time scales ~1/waves. Pre-committed:
// if durations stay ~44-57us at doubled occupancy, the ~8GB/s/CU cap is
// structural and the session is at its practical floor.

constexpr int BDIM = 256;
constexpr size_t IN_B = 8388608;   // floats per batch
constexpr int IN_D = 131072;       // floats per z-plane
constexpr int IN_H = 2048;         // floats per y-row
constexpr int M = 62;              // mag spatial dim
constexpr int F = 60;              // final spatial dim
constexpr int C = 32;
constexpr int MROW = M * C;                      // 1984 halves per mag row
constexpr size_t MAGSZ = (size_t)M * M * MROW;   // halves per mag buffer
constexpr size_t PLANE = (size_t)M * MROW;       // halves per mag z-plane
constexpr unsigned NPART = 2880;                 // 1440 P2 blocks x 2 batches

__device__ __forceinline__ float4 ld4(const float* p) {
    return *reinterpret_cast<const float4*>(p);
}
__device__ __forceinline__ float2 ldh2(const __half* p) {
    return __half22float2(*reinterpret_cast<const __half2*>(p));
}
__device__ __forceinline__ float4 sm3(float4 a, float4 b, float4 c) {
    return make_float4(a.x + 2.f * b.x + c.x, a.y + 2.f * b.y + c.y,
                       a.z + 2.f * b.z + c.z, a.w + 2.f * b.w + c.w);
}
__device__ __forceinline__ float4 df2(float4 a, float4 c) {
    return make_float4(c.x - a.x, c.y - a.y, c.z - a.z, c.w - a.w);
}

// ===================== Pass 1 (R7 body, verbatim; z-chunk 4) =====================
struct P1W { float4 A[2], B[2], C[2]; };

__device__ __forceinline__ void p1_plane(const float* __restrict__ col, size_t zoff,
                                         P1W& W)
{
    float4 S[4], D[4];
#pragma unroll
    for (int r = 0; r < 4; ++r) {
        const float* p = col + zoff + (size_t)r * IN_H;
        float4 a = ld4(p), b = ld4(p + C), c = ld4(p + 2 * C);
        S[r] = sm3(a, b, c);
        D[r] = df2(a, c);
    }
#pragma unroll
    for (int k = 0; k < 2; ++k) {
        W.A[k] = sm3(S[k], S[k+1], S[k+2]);
        W.B[k] = df2(S[k], S[k+2]);
        W.C[k] = sm3(D[k], D[k+1], D[k+2]);
    }
}

__device__ __forceinline__ void p1_emit(const P1W& W0, const P1W& W1, const P1W& W2,
                                        __half* __restrict__ mag, size_t cb,
                                        int z, int y0, bool wr)
{
    if (!wr) return;
#pragma unroll
    for (int k = 0; k < 2; ++k) {
        float4 gx = df2(W0.A[k], W2.A[k]);
        float4 gy = sm3(W0.B[k], W1.B[k], W2.B[k]);
        float4 gz = sm3(W0.C[k], W1.C[k], W2.C[k]);
        float m0 = sqrtf(gx.x * gx.x + gy.x * gy.x + gz.x * gz.x);
        float m1 = sqrtf(gx.y * gx.y + gy.y * gy.y + gz.y * gz.y);
        float m2 = sqrtf(gx.z * gx.z + gy.z * gy.z + gz.z * gz.z);
        float m3 = sqrtf(gx.w * gx.w + gy.w * gy.w + gz.w * gz.w);
        union { __half2 h[2]; float2 f; } u;
        u.h[0] = __floats2half2_rn(m0, m1);
        u.h[1] = __floats2half2_rn(m2, m3);
        *reinterpret_cast<float2*>(mag + ((size_t)z * M + (y0 + k)) * MROW + cb)
            = u.f;
    }
}

// zc in [0,16): z0 = zc*4, zn = min(4, M - z0) -> 4,4,...,4,2 (15*4+2 = 62).
__device__ __forceinline__ void p1_unit(const float* __restrict__ in,
                                        __half* __restrict__ mag,
                                        int b, int bx, int zc, int tid)
{
    const int xt = bx & 1, yt = bx >> 1;
    const int c4 = (tid & 7) << 2;           // channel base 0..28
    const int xl = tid >> 3;                 // 0..31
    const int x  = xt * 30 + xl;             // output x in [0,62)
    const bool wr = (xt == 0) || (xl >= 2);  // tile1 skips duplicated x=30,31
    const int y0 = yt * 2;
    const int z0 = zc * 4;
    const int zn = min(4, M - z0);           // 4, last chunk 2

    const float* col = in + (size_t)b * IN_B + (size_t)y0 * IN_H
                          + (size_t)x * C + c4;
    const size_t cb = (size_t)x * C + c4;

    P1W W0, W1, W2;
    p1_plane(col, (size_t)(z0 + 0) * IN_D, W0);
    p1_plane(col, (size_t)(z0 + 1) * IN_D, W1);
    int z = 0;
    while (true) {
        p1_plane(col, (size_t)(z0 + z + 2) * IN_D, W2);
        p1_emit(W0, W1, W2, mag, cb, z0 + z, y0, wr);
        if (++z >= zn) break;
        p1_plane(col, (size_t)(z0 + z + 2) * IN_D, W0);
        p1_emit(W1, W2, W0, mag, cb, z0 + z, y0, wr);
        if (++z >= zn) break;
        p1_plane(col, (size_t)(z0 + z + 2) * IN_D, W1);
        p1_emit(W2, W0, W1, mag, cb, z0 + z, y0, wr);
        if (++z >= zn) break;
        p1_plane(col, (size_t)(z0 + z + 2) * IN_D, W2);
        p1_emit(W0, W1, W2, mag, cb, z0 + z, y0, wr);
        if (++z >= zn) break;
    }
}

__global__ __launch_bounds__(BDIM) void sobel_mag_v12(
    const float* __restrict__ pred, const float* __restrict__ hr,
    __half* __restrict__ magP, __half* __restrict__ magH,
    int b, unsigned* __restrict__ counter, int zeroCtr)
{
    if (zeroCtr && blockIdx.x == 0 && blockIdx.y == 0 && blockIdx.z == 0 &&
        threadIdx.x == 0)
        __hip_atomic_store(counter, 0u, __ATOMIC_RELAXED,
                           __HIP_MEMORY_SCOPE_AGENT);
    const float* in = blockIdx.z ? hr : pred;
    __half* mag = blockIdx.z ? magH : magP;
    p1_unit(in, mag, b, blockIdx.x, blockIdx.y, threadIdx.x);
}

// ============ Pass 2 (R4 body, verbatim; z-chunk 5) ============
struct P2W { float2 A[2], B[2], C[2]; };

__device__ __forceinline__ void p2_plane(const __half* __restrict__ col, size_t zoff,
                                         P2W& W)
{
    float2 SX[4], DX[4];
#pragma unroll
    for (int j = 0; j < 4; ++j) {
        const __half* p = col + zoff + (size_t)j * MROW;
        float2 a = ldh2(p), b = ldh2(p + C), c = ldh2(p + 2 * C);
        SX[j] = make_float2(a.x + 2.f * b.x + c.x, a.y + 2.f * b.y + c.y);
        DX[j] = make_float2(c.x - a.x, c.y - a.y);
    }
#pragma unroll
    for (int k = 0; k < 2; ++k) {
        W.A[k] = make_float2(SX[k].x + 2.f * SX[k+1].x + SX[k+2].x,
                             SX[k].y + 2.f * SX[k+1].y + SX[k+2].y);
        W.B[k] = make_float2(SX[k+2].x - SX[k].x, SX[k+2].y - SX[k].y);
        W.C[k] = make_float2(DX[k].x + 2.f * DX[k+1].x + DX[k+2].x,
                             DX[k].y + 2.f * DX[k+1].y + DX[k+2].y);
    }
}

__device__ __forceinline__ void p2_emit(const P2W& P0, const P2W& P1, const P2W& P2,
                                        const P2W& H0, const P2W& H1, const P2W& H2,
                                        float& acc)
{
#pragma unroll
    for (int k = 0; k < 2; ++k) {
        float gxPx = P2.A[k].x - P0.A[k].x;
        float gxPy = P2.A[k].y - P0.A[k].y;
        float gyPx = P0.B[k].x + 2.f * P1.B[k].x + P2.B[k].x;
        float gyPy = P0.B[k].y + 2.f * P1.B[k].y + P2.B[k].y;
        float gzPx = P0.C[k].x + 2.f * P1.C[k].x + P2.C[k].x;
        float gzPy = P0.C[k].y + 2.f * P1.C[k].y + P2.C[k].y;
        float gxHx = H2.A[k].x - H0.A[k].x;
        float gxHy = H2.A[k].y - H0.A[k].y;
        float gyHx = H0.B[k].x + 2.f * H1.B[k].x + H2.B[k].x;
        float gyHy = H0.B[k].y + 2.f * H1.B[k].y + H2.B[k].y;
        float gzHx = H0.C[k].x + 2.f * H1.C[k].x + H2.C[k].x;
        float gzHy = H0.C[k].y + 2.f * H1.C[k].y + H2.C[k].y;
        float oPx = sqrtf(gxPx * gxPx + gyPx * gyPx) + gzPx * gzPx;
        float oPy = sqrtf(gxPy * gxPy + gyPy * gyPy) + gzPy * gzPy;
        float oHx = sqrtf(gxHx * gxHx + gyHx * gyHx) + gzHx * gzHx;
        float oHy = sqrtf(gxHy * gxHy + gyHy * gyHy) + gzHy * gzHy;
        acc += fabsf(oPx - oHx) + fabsf(oPy - oHy);
    }
}

// grid (120, 12): bx as in R4; zc in [0,12), z0 = zc*5, 5 outputs (planes z0..z0+6).
__global__ __launch_bounds__(BDIM) void sobel2_v12(
    const __half* __restrict__ magP, const __half* __restrict__ magH,
    int b, float* __restrict__ partial, unsigned* __restrict__ counter,
    float* __restrict__ out)
{
    const int xt = blockIdx.x & 3, yt = blockIdx.x >> 2;   // grid.x = 120
    const int zc = blockIdx.y;                             // [0,12)
    const int y0 = yt * 2;
    const int z0 = zc * 5;
    const int tid = threadIdx.x;
    const int xraw = xt * 16 + (tid >> 4);
    const bool xok = xraw < F;
    const int x = min(xraw, F - 1);
    const int c2 = (tid & 15) << 1;

    const size_t colo = (size_t)y0 * MROW + (size_t)x * C + c2;
    const __half* colP = magP + colo;
    const __half* colH = magH + colo;

    P2W P0, P1, P2, H0, H1, H2;
    p2_plane(colP, (size_t)(z0 + 0) * PLANE, P0);
    p2_plane(colH, (size_t)(z0 + 0) * PLANE, H0);
    p2_plane(colP, (size_t)(z0 + 1) * PLANE, P1);
    p2_plane(colH, (size_t)(z0 + 1) * PLANE, H1);
    float acc = 0.f;
    int z = 0;
    while (true) {
        p2_plane(colP, (size_t)(z0 + z + 2) * PLANE, P2);
        p2_plane(colH, (size_t)(z0 + z + 2) * PLANE, H2);
        if (xok) p2_emit(P0, P1, P2, H0, H1, H2, acc);
        if (++z >= 5) break;
        p2_plane(colP, (size_t)(z0 + z + 2) * PLANE, P0);
        p2_plane(colH, (size_t)(z0 + z + 2) * PLANE, H0);
        if (xok) p2_emit(P1, P2, P0, H1, H2, H0, acc);
        if (++z >= 5) break;
        p2_plane(colP, (size_t)(z0 + z + 2) * PLANE, P1);
        p2_plane(colH, (size_t)(z0 + z + 2) * PLANE, H1);
        if (xok) p2_emit(P2, P0, P1, H2, H0, H1, acc);
        if (++z >= 5) break;
    }

    // block reduction + globally-last-block finalize
    for (int o = 32; o > 0; o >>= 1) acc += __shfl_down(acc, o, 64);
    __shared__ float sred[BDIM / 64];
    __shared__ int isLast;
    __shared__ double sd[BDIM / 64];
    const int lane = tid & 63, wv = tid >> 6;
    if (lane == 0) sred[wv] = acc;
    __syncthreads();
    if (tid == 0) {
        float t = 0.f;
#pragma unroll
        for (int i = 0; i < BDIM / 64; ++i) t += sred[i];
        const size_t pidx = (size_t)b * 1440 + (size_t)zc * 120 + blockIdx.x;
        __hip_atomic_store(&partial[pidx], t, __ATOMIC_RELAXED,
                           __HIP_MEMORY_SCOPE_AGENT);
        const unsigned old = __hip_atomic_fetch_add(counter, 1u, __ATOMIC_ACQ_REL,
                                                    __HIP_MEMORY_SCOPE_AGENT);
        isLast = (old == NPART - 1u) ? 1 : 0;
    }
    __syncthreads();
    if (isLast) {
        double a = 0.0;
        for (unsigned i = tid; i < NPART; i += BDIM)
            a += (double)__hip_atomic_load(&partial[i], __ATOMIC_RELAXED,
                                           __HIP_MEMORY_SCOPE_AGENT);
        for (int o = 32; o > 0; o >>= 1) a += __shfl_down(a, o, 64);
        if (lane == 0) sd[wv] = a;
        __syncthreads();
        if (tid == 0) {
            double t = 0.0;
#pragma unroll
            for (int i = 0; i < BDIM / 64; ++i) t += sd[i];
            out[0] = (float)(t / 13824000.0);
        }
    }
}

extern "C" void kernel_launch(void* const* d_in, const int* in_sizes, int n_in,
                              void* d_out, int out_size, void* d_ws, size_t ws_size,
                              hipStream_t stream)
{
    const float* pred = (const float*)d_in[0];
    const float* hr   = (const float*)d_in[1];

    // ws layout: [0, 11.5KB): 2880 float partials
    //            [32KB): unsigned last-block counter (zeroed by P1(b0))
    //            [64KB, ...): 2 fp16 mag buffers (~29.2 MB), reused per batch
    float* partial    = (float*)d_ws;
    unsigned* counter = (unsigned*)((char*)d_ws + 32768);
    __half* magP = (__half*)((char*)d_ws + 65536);
    __half* magH = magP + MAGSZ;

    for (int b = 0; b < 2; ++b) {
        sobel_mag_v12<<<dim3(62, 16, 2), BDIM, 0, stream>>>(
            pred, hr, magP, magH, b, counter, b == 0 ? 1 : 0);
        sobel2_v12<<<dim3(120, 12), BDIM, 0, stream>>>(
            magP, magH, b, partial, counter, (float*)d_out);
    }
}